// Round 9
// baseline (356.927 us; speedup 1.0000x reference)
//
#include <hip/hip_runtime.h>
#include <hip/hip_bf16.h>

// ThresholdEncode: x (N floats in [0,1)) -> (N, 64) float32 spike matrix.
// Row j (j < N-1): col 2i   = (x[j] <= th[i]) & (x[j+1] >  th[i])  (up)
//                  col 2i+1 = (x[j] >  th[i]) & (x[j+1] <= th[i])  (down)
// th[i] = float32((i+1) * (1/33) in double)  -- matches np.linspace. Last row 0.
//
// === DIAGNOSTIC ROUND 3 (decisive) ===
// R8 learned: marginal streaming-store BW = 4.0 TB/s (64.5us / 256MB), and
// drain-overlap contaminates per-dispatch durations (fills slowed 155->170
// when we added ws traffic). Still no counters for OUR dispatch (152us < 170
// cutoff). Now: TWO extra passes into DISJOINT 256MB halves of d_ws ->
// kernel ~215us, guaranteed slowest dispatch -> top-5 shows our FETCH_SIZE /
// WRITE_SIZE / Occupancy / VALUBusy / hbm_gbps.
//   FETCH ~750MB => store RFO.  FETCH small + own hbm_gbps ~6TB/s => R5 was
//   already near-floor (drain contamination) -> revert R5, declare.
// NOTE: nontemporal stores LOST WRITES under graph replay (round 3) — plain
// stores only.

typedef float f32x4 __attribute__((ext_vector_type(4)));

__global__ __launch_bounds__(256) void ThresholdEncode_kernel(
    const float* __restrict__ x, f32x4* __restrict__ out,
    f32x4* __restrict__ ws, int n, int nws) {
    const int t = blockIdx.x * 256 + threadIdx.x;
    const int ngroups = (n + 7) >> 3;          // groups of 8 rows
    if (t >= ngroups * 16) return;
    const int c  = t & 15;                     // quad (4 cols) within row
    const int g  = t >> 4;                     // row group
    const int j0 = g << 3;                     // first row of group

    // Exact np.linspace(0,1,34,f32)[1:-1]: compute in double, round once.
    const float t0 = (float)((double)(2 * c + 1) * (1.0 / 33.0));
    const float t1 = (float)((double)(2 * c + 2) * (1.0 / 33.0));

    // Load x[j0 .. j0+8] : two aligned float4 + one boundary scalar.
    float xv[9];
    if (j0 + 8 <= n) {
        const f32x4 a = *(const f32x4*)(x + j0);
        const f32x4 b = *(const f32x4*)(x + j0 + 4);
        xv[0]=a.x; xv[1]=a.y; xv[2]=a.z; xv[3]=a.w;
        xv[4]=b.x; xv[5]=b.y; xv[6]=b.z; xv[7]=b.w;
        xv[8] = (j0 + 8 < n) ? x[j0 + 8] : 0.0f;
    } else {
        #pragma unroll
        for (int k = 0; k < 9; ++k) xv[k] = (j0 + k < n) ? x[j0 + k] : 0.0f;
    }

    // Compute all 8 output quads into registers (static indexing).
    f32x4 vv[8];
    #pragma unroll
    for (int k = 0; k < 8; ++k) {
        f32x4 v = (f32x4)(0.f, 0.f, 0.f, 0.f);
        if (j0 + k < n - 1) {
            const float xp = xv[k];
            const float xn = xv[k + 1];
            v.x = (xp <= t0 && xn >  t0) ? 1.0f : 0.0f;
            v.y = (xp >  t0 && xn <= t0) ? 1.0f : 0.0f;
            v.z = (xp <= t1 && xn >  t1) ? 1.0f : 0.0f;
            v.w = (xp >  t1 && xn <= t1) ? 1.0f : 0.0f;
        }
        vv[k] = v;
    }

    // Pass 1: real output.
    #pragma unroll
    for (int k = 0; k < 8; ++k)
        if (j0 + k < n) out[(j0 + k) * 16 + c] = vv[k];

    asm volatile("" ::: "memory");

    // Passes 2..: same data into disjoint 256MB regions of scratch — forces
    // our dispatch's true streaming-write BW into the profile. Same work
    // every call (nws depends only on ws_size).
    for (int p = 0; p < nws; ++p) {
        f32x4* w = ws + (size_t)p * (size_t)n * 16;
        #pragma unroll
        for (int k = 0; k < 8; ++k)
            if (j0 + k < n) w[(j0 + k) * 16 + c] = vv[k];
        asm volatile("" ::: "memory");
    }
}

extern "C" void kernel_launch(void* const* d_in, const int* in_sizes, int n_in,
                              void* d_out, int out_size, void* d_ws, size_t ws_size,
                              hipStream_t stream) {
    const float* x = (const float*)d_in[0];
    f32x4* out = (f32x4*)d_out;
    f32x4* ws  = (f32x4*)d_ws;
    const int n = in_sizes[0];                 // 1,000,000
    const size_t pass_bytes = (size_t)n * 16 * sizeof(f32x4);   // 256 MB
    int nws = (int)(ws_size / pass_bytes);     // how many disjoint regions fit
    if (nws > 2) nws = 2;                      // 2 extra passes suffice
    const int ngroups = (n + 7) >> 3;          // 125,000
    const int threads = ngroups * 16;          // 2,000,000
    const int block = 256;
    const int grid = (threads + block - 1) / block;  // 7,813 blocks
    ThresholdEncode_kernel<<<grid, block, 0, stream>>>(x, out, ws, n, nws);
}

// Round 10
// 245.159 us; speedup vs baseline: 1.4559x; 1.4559x over previous
//
#include <hip/hip_runtime.h>
#include <hip/hip_bf16.h>

// ThresholdEncode: x (N floats in [0,1)) -> (N, 64) float32 spike matrix.
// Row j (j < N-1): col 2i   = (x[j] <= th[i]) & (x[j+1] >  th[i])  (up)
//                  col 2i+1 = (x[j] >  th[i]) & (x[j+1] <= th[i])  (down)
// th[i] = float32((i+1) * (1/33) in double)  -- matches np.linspace. Last row 0.
//
// R9 findings: under rocprof's serialized replay our 3-pass kernel ran
// <163us on >1GB traffic => the kernel streams >6.3 TB/s in isolation; the
// in-graph gap is drain/contention accounting plus CU-side instruction cost
// (R4->R5: cutting load instrs 16x = -12us). This round: persistent grid
// (2048 wg = 8/CU, all resident, zero wg churn) + software-pipelined group
// loop (prefetch next group's x loads under current group's 8-store burst).
// NOTE: nontemporal stores LOST WRITES under graph replay (round 3) — plain
// stores only.

typedef float f32x4 __attribute__((ext_vector_type(4)));

__global__ __launch_bounds__(256) void ThresholdEncode_kernel(
    const float* __restrict__ x, f32x4* __restrict__ out, int n) {
    const int nthreads = gridDim.x * 256;      // 524,288
    const int t = blockIdx.x * 256 + threadIdx.x;
    const int ngroups = (n + 7) >> 3;          // 125,000 groups of 8 rows
    const int gstride = nthreads >> 4;         // groups advanced per iter: 32,768
    const int c = t & 15;                      // quad (4 cols) within row

    // Exact np.linspace(0,1,34,f32)[1:-1]: compute in double, round once.
    const float t0 = (float)((double)(2 * c + 1) * (1.0 / 33.0));
    const float t1 = (float)((double)(2 * c + 2) * (1.0 / 33.0));

    // Load x[j0 .. j0+8] for group gg (two aligned float4 + boundary scalar).
    auto loadg = [&](int gg, f32x4& A, f32x4& B, float& E) {
        const int j0 = gg << 3;
        if (j0 + 8 <= n) {                     // always true for n % 8 == 0
            A = *(const f32x4*)(x + j0);
            B = *(const f32x4*)(x + j0 + 4);
            E = (j0 + 8 < n) ? x[j0 + 8] : 0.0f;
        } else {
            float tmp[9];
            #pragma unroll
            for (int k = 0; k < 9; ++k) tmp[k] = (j0 + k < n) ? x[j0 + k] : 0.0f;
            A = (f32x4)(tmp[0], tmp[1], tmp[2], tmp[3]);
            B = (f32x4)(tmp[4], tmp[5], tmp[6], tmp[7]);
            E = tmp[8];
        }
    };

    int g = t >> 4;                            // first group for this thread
    if (g >= ngroups) return;

    f32x4 A, B; float E;
    loadg(g, A, B, E);                         // prologue load

    for (; g < ngroups; g += gstride) {
        // Prefetch next iteration's x window before the store burst.
        const int gn = g + gstride;
        f32x4 A2, B2; float E2 = 0.0f;
        if (gn < ngroups) loadg(gn, A2, B2, E2);

        const int j0 = g << 3;
        float xv[9] = {A.x, A.y, A.z, A.w, B.x, B.y, B.z, B.w, E};

        f32x4* o = out + (size_t)j0 * 16 + c;  // stores at o[k*16]
        #pragma unroll
        for (int k = 0; k < 8; ++k) {
            f32x4 v = (f32x4)(0.f, 0.f, 0.f, 0.f);
            if (j0 + k < n - 1) {
                const float xp = xv[k];
                const float xn = xv[k + 1];
                v.x = (xp <= t0 && xn >  t0) ? 1.0f : 0.0f;  // up   2c
                v.y = (xp >  t0 && xn <= t0) ? 1.0f : 0.0f;  // down 2c
                v.z = (xp <= t1 && xn >  t1) ? 1.0f : 0.0f;  // up   2c+1
                v.w = (xp >  t1 && xn <= t1) ? 1.0f : 0.0f;  // down 2c+1
            }
            if (j0 + k < n) o[k * 16] = v;
        }
        A = A2; B = B2; E = E2;
    }
}

extern "C" void kernel_launch(void* const* d_in, const int* in_sizes, int n_in,
                              void* d_out, int out_size, void* d_ws, size_t ws_size,
                              hipStream_t stream) {
    const float* x = (const float*)d_in[0];
    f32x4* out = (f32x4*)d_out;
    const int n = in_sizes[0];                 // 1,000,000
    const int block = 256;
    const int grid = 2048;                     // 8 wg/CU — fully resident, no churn
    ThresholdEncode_kernel<<<grid, block, 0, stream>>>(x, out, n);
}